// Round 5
// baseline (110.617 us; speedup 1.0000x reference)
//
#include <hip/hip_runtime.h>

// DotPred: score[t,e] = sum_d (x[src[t,e],d] - x[dst[t,e],d]) / sqrt(D)
//        = (rowsum(x)[src] - rowsum(x)[dst]) * (1/sqrt(D))
// Two-phase: (1) per-node rowsum into d_ws, (2) per-edge gather/subtract.
// Indices arrive as int32 (JAX x64 disabled; harness: integer -> const int*).
// Streaming accesses are nontemporal (native clang vector types — HIP_vector_type
// structs are rejected by __builtin_nontemporal_*) to keep S L2-resident.

#define IN_DIM 128
#define INV_SQRT_D 0.08838834764831843f  // 1/sqrt(128)

typedef float fx4 __attribute__((ext_vector_type(4)));
typedef int   ix4 __attribute__((ext_vector_type(4)));

// 32 lanes per row (float4 each = 128 floats), 2 rows per wave, 8 rows per 256-block.
__global__ void rowsum_kernel(const fx4* __restrict__ x4,
                              float* __restrict__ S, int n_nodes) {
    const int wave = (blockIdx.x * blockDim.x + threadIdx.x) >> 6;
    const int lane = threadIdx.x & 63;
    const int row  = wave * 2 + (lane >> 5);
    if (row >= n_nodes) return;
    const int col = lane & 31;

    // Nontemporal: x is read exactly once; don't let it evict S from L2.
    const fx4 v = __builtin_nontemporal_load(&x4[(size_t)row * (IN_DIM / 4) + col]);
    float s = (v.x + v.y) + (v.z + v.w);

    // Butterfly within each 32-lane half (xor of bits 0..4 stays in-half).
    #pragma unroll
    for (int off = 16; off > 0; off >>= 1)
        s += __shfl_xor(s, off, 64);

    if (col == 0) S[row] = s;   // regular store: S must stay cached
}

// 4 edges per thread: int4 index loads, float4 store, scalar tail folded in.
__global__ void edge_kernel4(const ix4* __restrict__ src4,
                             const ix4* __restrict__ dst4,
                             const int*  __restrict__ src,
                             const int*  __restrict__ dst,
                             const float* __restrict__ S,
                             fx4* __restrict__ out4,
                             float* __restrict__ out,
                             int n4, int n) {
    const int i = blockIdx.x * blockDim.x + threadIdx.x;
    if (i < n4) {
        const ix4 s = __builtin_nontemporal_load(&src4[i]);
        const ix4 d = __builtin_nontemporal_load(&dst4[i]);
        fx4 o;
        o.x = (S[s.x] - S[d.x]) * INV_SQRT_D;
        o.y = (S[s.y] - S[d.y]) * INV_SQRT_D;
        o.z = (S[s.z] - S[d.z]) * INV_SQRT_D;
        o.w = (S[s.w] - S[d.w]) * INV_SQRT_D;
        __builtin_nontemporal_store(o, &out4[i]);
    } else if (i == n4) {
        // Tail (n % 4 != 0) handled by one thread — n=1.5M makes this empty.
        for (int j = n4 * 4; j < n; ++j)
            out[j] = (S[src[j]] - S[dst[j]]) * INV_SQRT_D;
    }
}

extern "C" void kernel_launch(void* const* d_in, const int* in_sizes, int n_in,
                              void* d_out, int out_size, void* d_ws, size_t ws_size,
                              hipStream_t stream) {
    const float* x   = (const float*)d_in[0];
    const int*   src = (const int*)d_in[1];
    const int*   dst = (const int*)d_in[2];
    float* out = (float*)d_out;
    float* S   = (float*)d_ws;   // n_nodes floats of scratch (400 KB)

    const int n_nodes = in_sizes[0] / IN_DIM;   // 100000
    const int n_edges = in_sizes[1];            // T*E = 1.5M

    // Phase 1: rowsums. 8 rows per 256-thread block.
    const int grid1 = (n_nodes + 7) / 8;
    rowsum_kernel<<<grid1, 256, 0, stream>>>((const fx4*)x, S, n_nodes);

    // Phase 2: edge scores, 4 per thread (+1 thread covers any tail).
    const int n4 = n_edges >> 2;
    const int threads_needed = n4 + 1;
    const int grid2 = (threads_needed + 255) / 256;
    edge_kernel4<<<grid2, 256, 0, stream>>>((const ix4*)src, (const ix4*)dst,
                                            src, dst, S, (fx4*)out, out,
                                            n4, n_edges);
}